// Round 12
// baseline (1231.730 us; speedup 1.0000x reference)
//
#include <hip/hip_runtime.h>
#include <hip/hip_bf16.h>
#include <cstdint>
#include <cstddef>

typedef __bf16 bf16_t;
typedef __bf16 bf16x8 __attribute__((ext_vector_type(8)));
typedef float  f32x4  __attribute__((ext_vector_type(4)));
typedef float  f32x16 __attribute__((ext_vector_type(16)));

#define TOKENS 16384
#define HIDDEN 2048
#define FFN    8192

__device__ __forceinline__ void gload_lds16(const bf16_t* g, bf16_t* l) {
    __builtin_amdgcn_global_load_lds((const __attribute__((address_space(1))) void*)g,
                                     (__attribute__((address_space(3))) void*)l,
                                     16, 0, 0);
}

__global__ void cvt_f32_to_bf16(const float* __restrict__ in, bf16_t* __restrict__ out, int n8) {
    int i = blockIdx.x * blockDim.x + threadIdx.x;
    if (i >= n8) return;
    size_t base = (size_t)i * 8;
    f32x4 v0 = *(const f32x4*)&in[base];
    f32x4 v1 = *(const f32x4*)&in[base + 4];
    bf16x8 o;
    o[0] = (bf16_t)v0[0]; o[1] = (bf16_t)v0[1]; o[2] = (bf16_t)v0[2]; o[3] = (bf16_t)v0[3];
    o[4] = (bf16_t)v1[0]; o[5] = (bf16_t)v1[1]; o[6] = (bf16_t)v1[2]; o[7] = (bf16_t)v1[3];
    *(bf16x8*)&out[base] = o;
}

__global__ void transpose_cvt(const float* __restrict__ src, bf16_t* __restrict__ dst,
                              int R, int C) {
    __shared__ bf16_t tile[64][66];
    const int tcols = C >> 6;
    const int bx = blockIdx.x % tcols;
    const int by = blockIdx.x / tcols;
    const int c0 = bx << 6, r0 = by << 6;
    const int t = threadIdx.x;
#pragma unroll
    for (int i = 0; i < 16; ++i) {
        int idx = i * 256 + t;
        int rr = idx >> 6, cc = idx & 63;
        tile[rr][cc] = (bf16_t)src[(size_t)(r0 + rr) * C + (c0 + cc)];
    }
    __syncthreads();
#pragma unroll
    for (int i = 0; i < 16; ++i) {
        int idx = i * 256 + t;
        int cc = idx >> 6, rr = idx & 63;
        dst[(size_t)(c0 + cc) * R + (r0 + rr)] = tile[rr][cc];
    }
}

// ---------------------------------------------------------------------------
// 256x256 8-phase GEMM == round-11 kernel (passed) with the MFMA shape
// switched 16x16x32 -> 32x32x16 (+15% measured uarch throughput, half the
// instructions). Barriers, staging slots, vmcnt ledger, swizzle, liveness:
// byte-identical to the proven R4/R11 skeleton.
//
// Per-wave 128x64 output = 4 row-tiles(rt, 32 rows) x 2 col-tiles(ct, 32).
// Quadrant QM = rt-pair {0,1}/{2,3}; QN = ct. Per phase: 8 MFMAs
// (2 rt x 4 kh), reads 12/4/8/0 as before.
//
// Fragment maps (extension of the HW-verified 16x16 pattern):
//   A: lane l -> row l&31, k = (l>>5)*8 + j   (8 bf16 = 4 VGPRs)
//   B: lane l -> col l&31, k = (l>>5)*8 + j
//   C/D: col = lane&31, row = (reg&3) + 8*(reg>>2) + 4*(lane>>5)  [m74/m101]
// LDS element offset of an A frag (rt, kh) within the wave's 16KB A-half
// ([8 rowblk x 2 kblk] subtiles of 512 elems, st_16x32 swizzle):
//   (rt*2 + ((l>>4)&1))*1024 + (kh>>1)*512 + (l&15)*32
//     + (((kh&1)*16 + (l>>5)*8) ^ ((l&8)<<1))
// ---------------------------------------------------------------------------
#define BAR() __builtin_amdgcn_s_barrier()
#define VMW(n) asm volatile("s_waitcnt vmcnt(" #n ")" ::: "memory")
#define PRIO1() __builtin_amdgcn_s_setprio(1)
#define PRIO0() __builtin_amdgcn_s_setprio(0)

#define DS_A32(BUF, QM) do { \
    _Pragma("unroll") for (int rr = 0; rr < 2; ++rr) \
    _Pragma("unroll") for (int kh = 0; kh < 4; ++kh) \
        af[rr][kh] = *(const bf16x8*)&smem[(BUF)*16384 + wr*8192 + (((QM)*2+rr))*2048 + abase + kx[kh]]; \
} while (0)

#define DS_B32(BUF, CT, BB) do { \
    _Pragma("unroll") for (int kh = 0; kh < 4; ++kh) \
        BB[kh] = *(const bf16x8*)&smem[32768 + (BUF)*16384 + bhalf + (CT)*2048 + abase + kx[kh]]; \
} while (0)

#define MFMA_Q32(QM, QN, BB) do { \
    _Pragma("unroll") for (int kh = 0; kh < 4; ++kh) \
    _Pragma("unroll") for (int rr = 0; rr < 2; ++rr) \
        acc[(QM)*2+rr][QN] = __builtin_amdgcn_mfma_f32_32x32x16_bf16( \
            af[rr][kh], BB[kh], acc[(QM)*2+rr][QN], 0, 0, 0); \
} while (0)

// stage one half-tile (128 rows x 64 k = 8192 elems): 2 x global_load_lds/thread
#define STAGE(GBASE, HROWS, TILE, EOFF) do { \
    gload_lds16((GBASE) + aoff0 + (size_t)(HROWS) * K + (TILE) * 64, \
                &smem[(EOFF) + wave * 512]); \
    gload_lds16((GBASE) + aoff1 + (size_t)(HROWS) * K + (TILE) * 64, \
                &smem[(EOFF) + 4096 + wave * 512]); \
} while (0)

template<bool GELU_EPI, int M, int N, int K>
__global__ __launch_bounds__(512, 2)
void gemm32s(const bf16_t* __restrict__ A, const bf16_t* __restrict__ BT,
             const float* __restrict__ bias, void* __restrict__ out)
{
    constexpr int BM = 256, BN = 256;
    constexpr int NT = K / 64, NI = NT / 2;
    constexpr int NBN = N / BN;
    __shared__ __align__(128) bf16_t smem[65536];   // 128 KiB

    const int t = threadIdx.x;
    const int wave = t >> 6, lane = t & 63;
    const int wr = wave >> 2, wc = wave & 3;

    int wg = blockIdx.x;
    { const int cpx = (int)gridDim.x >> 3; wg = (wg & 7) * cpx + (wg >> 3); }
    const int bm = wg / NBN, bn = wg % NBN;
    const int rowA0 = bm * BM, colB0 = bn * BN;

    // staging source pre-swizzle (inverse st_16x32), proven rounds 4-11
    int sr0, sk0, sr1, sk1;
    {
        int o = t * 16;
        int ri = (o >> 6) & 15;
        int b = (o & 63) ^ ((ri & 8) << 2);
        sr0 = ((o >> 10) >> 1) * 16 + ri;
        sk0 = ((o >> 10) & 1) * 32 + (b >> 1);
        o = 8192 + t * 16;
        ri = (o >> 6) & 15;
        b = (o & 63) ^ ((ri & 8) << 2);
        sr1 = ((o >> 10) >> 1) * 16 + ri;
        sk1 = ((o >> 10) & 1) * 32 + (b >> 1);
    }
    const bf16_t* gA0 = A + (size_t)rowA0 * K;
    const bf16_t* gB0 = BT + (size_t)colB0 * K;
    const size_t aoff0 = (size_t)sr0 * K + sk0;
    const size_t aoff1 = (size_t)sr1 * K + sk1;

    // 32x32 fragment read addressing (swizzled), per-lane:
    const int ri32 = lane & 15;
    const int a_rb = (lane >> 4) & 1;       // row sub-block within 32-row tile
    const int kq   = lane >> 5;             // k-quad (0/1): +8 elems
    const int swz  = (lane & 8) << 1;       // element-XOR for st_16x32
    const int abase = a_rb * 1024 + ri32 * 32;
    int kx[4];
#pragma unroll
    for (int kh = 0; kh < 4; ++kh)
        kx[kh] = (kh >> 1) * 512 + (((kh & 1) * 16 + kq * 8) ^ swz);
    const int bhalf = (wc >> 1) * 8192 + (wc & 1) * 4096;

    f32x16 acc[4][2] = {};
    bf16x8 af[2][4], b0[4], b1[4];

    // prologue: t0 fully + t1.A0/B0/B1; drain t0
    STAGE(gA0, 0,   0, 0);          // t0.A0
    STAGE(gA0, 128, 0, 8192);       // t0.A1
    STAGE(gB0, 0,   0, 32768);      // t0.B0
    STAGE(gB0, 128, 0, 40960);      // t0.B1
    STAGE(gA0, 0,   1, 16384);      // t1.A0
    STAGE(gB0, 0,   1, 49152);      // t1.B0
    STAGE(gB0, 128, 1, 57344);      // t1.B1
    VMW(6);                         // t0 landed; t1's 6 loads in flight
    BAR();

    for (int i = 0; i < NI - 1; ++i) {
        const int t1 = 2 * i + 1, t2 = 2 * i + 2, t3 = 2 * i + 3;
        // P1: Q(rt01, ct0) on buf0
        DS_A32(0, 0); DS_B32(0, 0, b0);
        STAGE(gA0, 128, t1, 24576);            // buf1.A1 <- t1.A1
        BAR();
        PRIO1(); MFMA_Q32(0, 0, b0); PRIO0();
        BAR();
        // P2: Q(rt01, ct1)
        DS_B32(0, 1, b1);
        BAR();
        PRIO1(); MFMA_Q32(0, 1, b1); PRIO0();
        BAR();
        // P3: Q(rt23, ct1) (buf0.B free after P2)
        DS_A32(0, 1);
        STAGE(gB0, 0, t2, 32768);              // buf0.B0 <- t2.B0
        BAR();
        PRIO1(); MFMA_Q32(1, 1, b1); PRIO0();
        BAR();
        // P4: Q(rt23, ct0) regs-only (buf0.A free after P3)
        STAGE(gB0, 128, t2, 40960);            // buf0.B1 <- t2.B1
        STAGE(gA0, 0,   t2, 0);                // buf0.A0 <- t2.A0
        VMW(6);                                // all t1 landed
        BAR();
        PRIO1(); MFMA_Q32(1, 0, b0); PRIO0();
        BAR();
        // P5: Q(rt01, ct0) on buf1
        DS_A32(1, 0); DS_B32(1, 0, b0);
        STAGE(gA0, 128, t2, 8192);             // buf0.A1 <- t2.A1
        BAR();
        PRIO1(); MFMA_Q32(0, 0, b0); PRIO0();
        BAR();
        // P6: Q(rt01, ct1)
        DS_B32(1, 1, b1);
        BAR();
        PRIO1(); MFMA_Q32(0, 1, b1); PRIO0();
        BAR();
        // P7: Q(rt23, ct1) (buf1.B free after P6)
        DS_A32(1, 1);
        STAGE(gB0, 0, t3, 49152);              // buf1.B0 <- t3.B0
        BAR();
        PRIO1(); MFMA_Q32(1, 1, b1); PRIO0();
        BAR();
        // P8: Q(rt23, ct0) (buf1.A free after P7)
        STAGE(gB0, 128, t3, 57344);            // buf1.B1 <- t3.B1
        STAGE(gA0, 0,   t3, 16384);            // buf1.A0 <- t3.A0
        VMW(6);                                // all t2 landed
        BAR();
        PRIO1(); MFMA_Q32(1, 0, b0); PRIO0();
        BAR();
    }

    // peeled last iteration: tiles NT-2 (buf0), NT-1 (buf1)
    DS_A32(0, 0); DS_B32(0, 0, b0);
    STAGE(gA0, 128, NT - 1, 24576);            // buf1.A1 <- (NT-1).A1
    BAR();
    PRIO1(); MFMA_Q32(0, 0, b0); PRIO0();
    BAR();
    DS_B32(0, 1, b1);
    BAR();
    PRIO1(); MFMA_Q32(0, 1, b1); PRIO0();
    BAR();
    DS_A32(0, 1);
    BAR();
    PRIO1(); MFMA_Q32(1, 1, b1); PRIO0();
    BAR();
    VMW(0);                                    // last tile fully landed
    BAR();
    PRIO1(); MFMA_Q32(1, 0, b0); PRIO0();
    BAR();
    DS_A32(1, 0); DS_B32(1, 0, b0);
    BAR();
    PRIO1(); MFMA_Q32(0, 0, b0); PRIO0();
    BAR();
    DS_B32(1, 1, b1);
    BAR();
    PRIO1(); MFMA_Q32(0, 1, b1); PRIO0();
    BAR();
    DS_A32(1, 1);
    BAR();
    PRIO1(); MFMA_Q32(1, 1, b1); PRIO0();
    MFMA_Q32(1, 0, b0);

    // epilogue: 32x32 C/D layout col=lane&31, row=(reg&3)+8*(reg>>2)+4*(lane>>5)
    const int orow = rowA0 + wr * 128;
    const int ocol = colB0 + wc * 64 + (lane & 31);
#pragma unroll
    for (int rt = 0; rt < 4; ++rt) {
#pragma unroll
        for (int ct = 0; ct < 2; ++ct) {
            const int c = ocol + ct * 32;
            const float bv = bias[c];
#pragma unroll
            for (int reg = 0; reg < 16; ++reg) {
                const int r = orow + rt * 32 + (reg & 3) + 8 * (reg >> 2) + 4 * kq;
                float xv = acc[rt][ct][reg] + bv;
                if constexpr (GELU_EPI) {
                    float g = 0.5f * xv * (1.0f + erff(xv * 0.70710678118654752f));
                    ((bf16_t*)out)[(size_t)r * N + c] = (bf16_t)g;
                } else {
                    ((float*)out)[(size_t)r * N + c] = xv;
                }
            }
        }
    }
}

extern "C" void kernel_launch(void* const* d_in, const int* in_sizes, int n_in,
                              void* d_out, int out_size, void* d_ws, size_t ws_size,
                              hipStream_t stream) {
    const float* x  = (const float*)d_in[0];
    const float* w1 = (const float*)d_in[1];
    const float* b1 = (const float*)d_in[2];
    const float* w2 = (const float*)d_in[3];
    const float* b2 = (const float*)d_in[4];
    float* y = (float*)d_out;

    const size_t xb_elems  = (size_t)TOKENS * HIDDEN;
    const size_t w1t_elems = (size_t)FFN * HIDDEN;
    const size_t w2t_elems = (size_t)HIDDEN * FFN;
    const size_t h_elems   = (size_t)TOKENS * FFN;
    const size_t need = (xb_elems + w1t_elems + w2t_elems + h_elems) * sizeof(bf16_t);
    if (ws_size < need) return;

    char* ws = (char*)d_ws;
    bf16_t* xb  = (bf16_t*)ws;
    bf16_t* w1t = xb + xb_elems;
    bf16_t* w2t = w1t + w1t_elems;
    bf16_t* h   = w2t + w2t_elems;

    cvt_f32_to_bf16<<<(TOKENS * HIDDEN / 8 + 255) / 256, 256, 0, stream>>>(
        x, xb, TOKENS * HIDDEN / 8);
    transpose_cvt<<<(HIDDEN / 64) * (FFN / 64), 256, 0, stream>>>(w1, w1t, HIDDEN, FFN);
    transpose_cvt<<<(FFN / 64) * (HIDDEN / 64), 256, 0, stream>>>(w2, w2t, FFN, HIDDEN);

    gemm32s<true, TOKENS, FFN, HIDDEN>
        <<<(TOKENS / 256) * (FFN / 256), 512, 0, stream>>>(xb, w1t, b1, h);
    gemm32s<false, TOKENS, HIDDEN, FFN>
        <<<(TOKENS / 256) * (HIDDEN / 256), 512, 0, stream>>>(h, w2t, b2, y);
}